// Round 1
// baseline (1093.307 us; speedup 1.0000x reference)
//
#include <hip/hip_runtime.h>
#include <cstdint>
#include <cstddef>

#define M_DIM 4096
#define N_DIM 16384
#define K_DIM 4096
#define NBLK_Q 128

typedef __bf16 bf16x8 __attribute__((ext_vector_type(8)));
typedef float f32x4 __attribute__((ext_vector_type(4)));
typedef unsigned short u16x8 __attribute__((ext_vector_type(8)));

__device__ __forceinline__ unsigned short f2bf(float f) {
  unsigned int u = __builtin_bit_cast(unsigned int, f);
  u += 0x7fffu + ((u >> 16) & 1u);
  return (unsigned short)(u >> 16);
}

__device__ __forceinline__ void async_copy16(const void* g, void* l) {
  __builtin_amdgcn_global_load_lds((__attribute__((address_space(1))) void*)g,
                                   (__attribute__((address_space(3))) void*)l,
                                   16, 0, 0);
}

// ---------------- pre-pass 1: x fp32 -> bf16 (A matrix [M][K]) ----------------
__global__ __launch_bounds__(256) void cvt_x_bf16(const float4* __restrict__ x,
                                                  ushort4* __restrict__ A) {
  int tid = blockIdx.x * 256 + threadIdx.x;  // each handles 4 floats
  float4 v = x[tid];
  ushort4 o;
  o.x = f2bf(v.x); o.y = f2bf(v.y); o.z = f2bf(v.z); o.w = f2bf(v.w);
  A[tid] = o;
}

// ------------- pre-pass 2: dequantize qs int32 + scales -> W bf16 [N][K] -------------
__global__ __launch_bounds__(256) void dequant_w(const int* __restrict__ qs,
                                                 const float* __restrict__ scales,
                                                 unsigned short* __restrict__ W) {
  size_t tid = (size_t)blockIdx.x * 256 + threadIdx.x;  // each handles 8 elements
  size_t e = tid * 8;
  size_t o = e >> 12;                 // row (output channel), K=4096
  int nb = ((int)(e & 4095)) >> 5;    // block-of-32 index
  float s = scales[o * NBLK_Q + nb];
  const int4* q = (const int4*)(qs + e);
  int4 q0 = q[0], q1 = q[1];
  u16x8 out;
  out[0] = f2bf(s * (float)q0.x);
  out[1] = f2bf(s * (float)q0.y);
  out[2] = f2bf(s * (float)q0.z);
  out[3] = f2bf(s * (float)q0.w);
  out[4] = f2bf(s * (float)q1.x);
  out[5] = f2bf(s * (float)q1.y);
  out[6] = f2bf(s * (float)q1.z);
  out[7] = f2bf(s * (float)q1.w);
  *(u16x8*)(W + e) = out;
}

// ---------------- main GEMM: C[M][N] = A[M][K] * Bt[N][K]^T + bias ----------------
// m97 structure: 128x128 tile, BK=32, 4 waves, 16x16x32 bf16 MFMA, 4x4 frags/wave.
// LDS is laid out fragment-contiguous (16 fragments x 1024B): fragment fi holds
// rows 16*fi..16*fi+15 (A for fi<8, Bt for fi>=8) of the current K-slab, in MFMA
// lane order: byte (g*16+r)*16 + j*2 holds element [row=r][k=8g+j]. Staged via
// global_load_lds (wave-uniform base + lane*16) with pre-swizzled global src.
__global__ __launch_bounds__(256) void gemm_bt_bias(
    const unsigned short* __restrict__ A,   // [M][K] bf16
    const unsigned short* __restrict__ Bt,  // [N][K] bf16
    const float* __restrict__ bias,         // [N]
    float* __restrict__ C) {                // [M][N] fp32
  __shared__ unsigned short lds[16 * 512];  // 16 KB

  const int tid = threadIdx.x;
  const int w = tid >> 6;   // wave 0..3
  const int l = tid & 63;
  const int r = l & 15;
  const int g = l >> 4;

  // bijective XCD swizzle: nwg = 4096, divisible by 8
  const int nwg = gridDim.x;
  const int cpx = nwg >> 3;
  const int bid = blockIdx.x;
  const int wgid = (bid & 7) * cpx + (bid >> 3);
  const int ntile = wgid % (N_DIM / 128);
  const int mtile = wgid / (N_DIM / 128);
  const int brow = mtile * 128;
  const int bcol = ntile * 128;

  const int wm = w >> 1;  // wave's 64x64 quadrant
  const int wn = w & 1;

  // per-thread staging sources: issue i covers fragment fi = i*4 + w
  const unsigned short* srcs[4];
  unsigned short* ldst[4];
#pragma unroll
  for (int i = 0; i < 4; ++i) {
    int fi = i * 4 + w;
    if (fi < 8)
      srcs[i] = A + (size_t)(brow + fi * 16 + r) * K_DIM + 8 * g;
    else
      srcs[i] = Bt + (size_t)(bcol + (fi - 8) * 16 + r) * K_DIM + 8 * g;
    ldst[i] = &lds[fi * 512];
  }

  f32x4 acc[4][4] = {};

  for (int kt = 0; kt < K_DIM / 32; ++kt) {
#pragma unroll
    for (int i = 0; i < 4; ++i) {
      async_copy16(srcs[i] + kt * 32, ldst[i]);
    }
    __syncthreads();  // drains vmcnt -> LDS tile ready

    bf16x8 a[4], b[4];
#pragma unroll
    for (int i = 0; i < 4; ++i)
      a[i] = *(const bf16x8*)&lds[(wm * 4 + i) * 512 + l * 8];
#pragma unroll
    for (int j = 0; j < 4; ++j)
      b[j] = *(const bf16x8*)&lds[(8 + wn * 4 + j) * 512 + l * 8];

#pragma unroll
    for (int i = 0; i < 4; ++i)
#pragma unroll
      for (int j = 0; j < 4; ++j)
        acc[i][j] = __builtin_amdgcn_mfma_f32_16x16x32_bf16(a[i], b[j], acc[i][j], 0, 0, 0);

    __syncthreads();  // protect LDS before next stage
  }

  // epilogue: C/D layout col = lane&15, row = (lane>>4)*4 + t
#pragma unroll
  for (int j = 0; j < 4; ++j) {
    const int col = bcol + wn * 64 + j * 16 + r;
    const float bv = bias[col];
#pragma unroll
    for (int i = 0; i < 4; ++i) {
      const int row = brow + wm * 64 + i * 16 + g * 4;
#pragma unroll
      for (int t = 0; t < 4; ++t) {
        C[(size_t)(row + t) * N_DIM + col] = acc[i][j][t] + bv;
      }
    }
  }
}

// ---------------- fallback (ws too small): exact fp32, slow but correct ----------------
__global__ void naive_gemm(const float* __restrict__ x, const int* __restrict__ qs,
                           const float* __restrict__ scales, const float* __restrict__ bias,
                           float* __restrict__ y) {
  size_t idx = (size_t)blockIdx.x * 256 + threadIdx.x;
  if (idx >= (size_t)M_DIM * N_DIM) return;
  int o = (int)(idx % N_DIM);
  size_t m = idx / N_DIM;
  const float* xr = x + m * K_DIM;
  const int* q = qs + (size_t)o * K_DIM;
  const float* sc = scales + (size_t)o * NBLK_Q;
  float sum = 0.f;
  for (int nb = 0; nb < NBLK_Q; ++nb) {
    float s = sc[nb];
    float bs = 0.f;
#pragma unroll 8
    for (int b = 0; b < 32; ++b) bs += xr[nb * 32 + b] * (float)q[nb * 32 + b];
    sum += s * bs;
  }
  y[idx] = sum + bias[o];
}

extern "C" void kernel_launch(void* const* d_in, const int* in_sizes, int n_in,
                              void* d_out, int out_size, void* d_ws, size_t ws_size,
                              hipStream_t stream) {
  const float* x = (const float*)d_in[0];
  const int* qs = (const int*)d_in[1];
  const float* scales = (const float*)d_in[2];
  const float* bias = (const float*)d_in[3];
  float* y = (float*)d_out;

  const size_t A_bytes = (size_t)M_DIM * K_DIM * 2;  // 32 MB
  const size_t W_bytes = (size_t)N_DIM * K_DIM * 2;  // 128 MB

  if (ws_size < A_bytes + W_bytes) {
    size_t total = (size_t)M_DIM * N_DIM;
    naive_gemm<<<(unsigned)((total + 255) / 256), 256, 0, stream>>>(x, qs, scales, bias, y);
    return;
  }

  unsigned short* A = (unsigned short*)d_ws;
  unsigned short* W = (unsigned short*)((char*)d_ws + A_bytes);

  cvt_x_bf16<<<(M_DIM * K_DIM / 4) / 256, 256, 0, stream>>>((const float4*)x, (ushort4*)A);
  dequant_w<<<(int)(((size_t)N_DIM * K_DIM / 8) / 256), 256, 0, stream>>>(qs, scales, W);
  gemm_bt_bias<<<(M_DIM / 128) * (N_DIM / 128), 256, 0, stream>>>(A, W, bias, y);
}

// Round 2
// 765.067 us; speedup vs baseline: 1.4290x; 1.4290x over previous
//
#include <hip/hip_runtime.h>
#include <cstdint>
#include <cstddef>

#define M_DIM 4096
#define N_DIM 16384
#define K_DIM 4096
#define NBLK_Q 128

#define BM 256
#define BN 256
#define BK 32
#define KTILES (K_DIM / BK)  // 128

typedef __bf16 bf16x8 __attribute__((ext_vector_type(8)));
typedef float f32x4 __attribute__((ext_vector_type(4)));
typedef unsigned short u16x8 __attribute__((ext_vector_type(8)));

__device__ __forceinline__ unsigned short f2bf(float f) {
  unsigned int u = __builtin_bit_cast(unsigned int, f);
  u += 0x7fffu + ((u >> 16) & 1u);
  return (unsigned short)(u >> 16);
}

__device__ __forceinline__ void async_copy16(const void* g, void* l) {
  __builtin_amdgcn_global_load_lds((__attribute__((address_space(1))) void*)g,
                                   (__attribute__((address_space(3))) void*)l,
                                   16, 0, 0);
}

// ---------------- pre-pass 1: x fp32 -> bf16 (A matrix [M][K]) ----------------
__global__ __launch_bounds__(256) void cvt_x_bf16(const float4* __restrict__ x,
                                                  ushort4* __restrict__ A) {
  int tid = blockIdx.x * 256 + threadIdx.x;
  float4 v = x[tid];
  ushort4 o;
  o.x = f2bf(v.x); o.y = f2bf(v.y); o.z = f2bf(v.z); o.w = f2bf(v.w);
  A[tid] = o;
}

// ------------- pre-pass 2: dequantize qs int32 + scales -> W bf16 [N][K] -------------
__global__ __launch_bounds__(256) void dequant_w(const int* __restrict__ qs,
                                                 const float* __restrict__ scales,
                                                 unsigned short* __restrict__ W) {
  size_t tid = (size_t)blockIdx.x * 256 + threadIdx.x;
  size_t e = tid * 8;
  size_t o = e >> 12;
  int nb = ((int)(e & 4095)) >> 5;
  float s = scales[o * NBLK_Q + nb];
  const int4* q = (const int4*)(qs + e);
  int4 q0 = q[0], q1 = q[1];
  u16x8 out;
  out[0] = f2bf(s * (float)q0.x);
  out[1] = f2bf(s * (float)q0.y);
  out[2] = f2bf(s * (float)q0.z);
  out[3] = f2bf(s * (float)q0.w);
  out[4] = f2bf(s * (float)q1.x);
  out[5] = f2bf(s * (float)q1.y);
  out[6] = f2bf(s * (float)q1.z);
  out[7] = f2bf(s * (float)q1.w);
  *(u16x8*)(W + e) = out;
}

// ---------------- main GEMM: C[M][N] = A[M][K] * Bt[N][K]^T + bias ----------------
// 256x256 tile, BK=32, 8 waves (2M x 4N), per-wave output 128x64 (8x4 frags of
// 16x16x32 bf16 MFMA). Fragment-contiguous LDS (0 bank conflicts): buffer =
// 32 A-frags + 32 B-frags... (16 each), 1KB per frag, lane s holds row (s&15),
// k = 8*(s>>4)..+7, staged via global_load_lds with pre-swizzled global source
// (wave w's issue i writes exactly one fragment: uniform base + lane*16).
// Pipeline: 4 LDS buffers (128KB), loads issued 3 K-tiles ahead, counted
// s_waitcnt vmcnt(8) at each tile boundary (never 0 in the loop), one barrier
// per tile, s_setprio(1) around the MFMA cluster.
__global__ __launch_bounds__(512) void gemm_bt_bias(
    const unsigned short* __restrict__ A,   // [M][K] bf16
    const unsigned short* __restrict__ Bt,  // [N][K] bf16
    const float* __restrict__ bias,         // [N]
    float* __restrict__ C) {                // [M][N] fp32
  __shared__ unsigned short lds[4][16384];  // 4 x 32KB = 128KB

  const int tid = threadIdx.x;
  const int w = tid >> 6;       // wave 0..7
  const int l = tid & 63;
  const int wm = w >> 2;        // 0..1  (M half)
  const int wn = w & 3;         // 0..3  (N quarter)
  const int sr = l & 15;
  const int sg = l >> 4;

  // grid order: XCD-chunked (bijective, nwg=1024 % 8 == 0), mtile fastest
  // within each chunk so concurrent blocks on an XCD share W-tiles (L2) and
  // A stays L3-resident.
  const int bid = blockIdx.x;
  const int wgid = (bid & 7) * 128 + (bid >> 3);
  const int mtile = wgid & 15;   // 16 mtiles (M/256)
  const int ntile = wgid >> 4;   // 64 ntiles (N/256)
  const int brow = mtile * BM;
  const int bcol = ntile * BN;

  // staging: 4 global_load_lds per thread per K-tile; wave w's issue i fills
  // fragment f = (i&1)*8 + w of A (i<2) or Bt (i>=2).
  const unsigned short* src[4];
  int ldsoff[4];  // byte offset within one 32KB buffer
#pragma unroll
  for (int i = 0; i < 4; ++i) {
    const int f = ((i & 1) << 3) + w;  // 0..15
    if (i < 2) {
      src[i] = A + (size_t)(brow + f * 16 + sr) * K_DIM + sg * 8;
      ldsoff[i] = f * 1024;
    } else {
      src[i] = Bt + (size_t)(bcol + f * 16 + sr) * K_DIM + sg * 8;
      ldsoff[i] = (16 + f) * 1024;
    }
  }

  f32x4 acc[8][4] = {};

  // prologue: prefetch tiles 0,1,2
#pragma unroll
  for (int t = 0; t < 3; ++t) {
    char* bufp = (char*)&lds[t & 3][0];
#pragma unroll
    for (int i = 0; i < 4; ++i) async_copy16(src[i] + t * BK, bufp + ldsoff[i]);
  }
  asm volatile("s_waitcnt vmcnt(8)" ::: "memory");
  __builtin_amdgcn_s_barrier();
  asm volatile("" ::: "memory");

  for (int kt = 0; kt < KTILES; ++kt) {
    // issue loads for tile kt+3 (wraps harmlessly at the tail; buffer parity
    // is consistent since KTILES % 4 == 0)
    {
      const int t = (kt + 3) & (KTILES - 1);
      char* bufp = (char*)&lds[t & 3][0];
#pragma unroll
      for (int i = 0; i < 4; ++i) async_copy16(src[i] + t * BK, bufp + ldsoff[i]);
    }

    const char* bufp = (const char*)&lds[kt & 3][0];
    bf16x8 a[8], b[4];
#pragma unroll
    for (int i = 0; i < 8; ++i)
      a[i] = *(const bf16x8*)(bufp + ((wm * 8 + i) * 1024 + l * 16));
#pragma unroll
    for (int j = 0; j < 4; ++j)
      b[j] = *(const bf16x8*)(bufp + ((16 + wn * 4 + j) * 1024 + l * 16));

    __builtin_amdgcn_s_setprio(1);
#pragma unroll
    for (int i = 0; i < 8; ++i)
#pragma unroll
      for (int j = 0; j < 4; ++j)
        acc[i][j] = __builtin_amdgcn_mfma_f32_16x16x32_bf16(a[i], b[j], acc[i][j], 0, 0, 0);
    __builtin_amdgcn_s_setprio(0);

    // counted wait: 12 outstanding max, oldest 4 (tile kt+1) must land.
    asm volatile("s_waitcnt vmcnt(8)" ::: "memory");
    __builtin_amdgcn_s_barrier();
    asm volatile("" ::: "memory");
  }

  asm volatile("s_waitcnt vmcnt(0)" ::: "memory");

  // epilogue: C/D layout col = lane&15, row = (lane>>4)*4 + t
#pragma unroll
  for (int j = 0; j < 4; ++j) {
    const int col = bcol + wn * 64 + j * 16 + sr;
    const float bv = bias[col];
#pragma unroll
    for (int i = 0; i < 8; ++i) {
      const int row = brow + wm * 128 + i * 16 + sg * 4;
#pragma unroll
      for (int t = 0; t < 4; ++t) {
        C[(size_t)(row + t) * N_DIM + col] = acc[i][j][t] + bv;
      }
    }
  }
}

// ---------------- fallback (ws too small): exact fp32, slow but correct ----------------
__global__ void naive_gemm(const float* __restrict__ x, const int* __restrict__ qs,
                           const float* __restrict__ scales, const float* __restrict__ bias,
                           float* __restrict__ y) {
  size_t idx = (size_t)blockIdx.x * 256 + threadIdx.x;
  if (idx >= (size_t)M_DIM * N_DIM) return;
  int o = (int)(idx % N_DIM);
  size_t m = idx / N_DIM;
  const float* xr = x + m * K_DIM;
  const int* q = qs + (size_t)o * K_DIM;
  const float* sc = scales + (size_t)o * NBLK_Q;
  float sum = 0.f;
  for (int nb = 0; nb < NBLK_Q; ++nb) {
    float s = sc[nb];
    float bs = 0.f;
#pragma unroll 8
    for (int b = 0; b < 32; ++b) bs += xr[nb * 32 + b] * (float)q[nb * 32 + b];
    sum += s * bs;
  }
  y[idx] = sum + bias[o];
}

extern "C" void kernel_launch(void* const* d_in, const int* in_sizes, int n_in,
                              void* d_out, int out_size, void* d_ws, size_t ws_size,
                              hipStream_t stream) {
  const float* x = (const float*)d_in[0];
  const int* qs = (const int*)d_in[1];
  const float* scales = (const float*)d_in[2];
  const float* bias = (const float*)d_in[3];
  float* y = (float*)d_out;

  const size_t A_bytes = (size_t)M_DIM * K_DIM * 2;  // 32 MB
  const size_t W_bytes = (size_t)N_DIM * K_DIM * 2;  // 128 MB

  if (ws_size < A_bytes + W_bytes) {
    size_t total = (size_t)M_DIM * N_DIM;
    naive_gemm<<<(unsigned)((total + 255) / 256), 256, 0, stream>>>(x, qs, scales, bias, y);
    return;
  }

  unsigned short* A = (unsigned short*)d_ws;
  unsigned short* W = (unsigned short*)((char*)d_ws + A_bytes);

  cvt_x_bf16<<<(M_DIM * K_DIM / 4) / 256, 256, 0, stream>>>((const float4*)x, (ushort4*)A);
  dequant_w<<<(int)(((size_t)N_DIM * K_DIM / 8) / 256), 256, 0, stream>>>(qs, scales, W);
  gemm_bt_bias<<<(M_DIM / BM) * (N_DIM / BN), 512, 0, stream>>>(A, W, bias, y);
}

// Round 3
// 748.602 us; speedup vs baseline: 1.4605x; 1.0220x over previous
//
#include <hip/hip_runtime.h>
#include <cstdint>
#include <cstddef>

#define M_DIM 4096
#define N_DIM 16384
#define K_DIM 4096
#define NBLK_Q 128

#define BM 256
#define BN 256
#define BK 64
#define KTILES (K_DIM / BK)   // 64
#define NGROUPS (KTILES * 4)  // 256 half-tiles (16KB groups)

typedef __bf16 bf16x8 __attribute__((ext_vector_type(8)));
typedef float f32x4 __attribute__((ext_vector_type(4)));
typedef unsigned short u16x8 __attribute__((ext_vector_type(8)));

__device__ __forceinline__ unsigned short f2bf(float f) {
  unsigned int u = __builtin_bit_cast(unsigned int, f);
  u += 0x7fffu + ((u >> 16) & 1u);
  return (unsigned short)(u >> 16);
}

__device__ __forceinline__ void async_copy16(const void* g, void* l) {
  __builtin_amdgcn_global_load_lds((__attribute__((address_space(1))) void*)g,
                                   (__attribute__((address_space(3))) void*)l,
                                   16, 0, 0);
}

// ---------------- pre-pass 1: x fp32 -> bf16 (A matrix [M][K]) ----------------
__global__ __launch_bounds__(256) void cvt_x_bf16(const float4* __restrict__ x,
                                                  ushort4* __restrict__ A) {
  int tid = blockIdx.x * 256 + threadIdx.x;
  float4 v = x[tid];
  ushort4 o;
  o.x = f2bf(v.x); o.y = f2bf(v.y); o.z = f2bf(v.z); o.w = f2bf(v.w);
  A[tid] = o;
}

// ------------- pre-pass 2: dequantize qs int32 + scales -> W bf16 [N][K] -------------
__global__ __launch_bounds__(256) void dequant_w(const int* __restrict__ qs,
                                                 const float* __restrict__ scales,
                                                 unsigned short* __restrict__ W) {
  size_t tid = (size_t)blockIdx.x * 256 + threadIdx.x;
  size_t e = tid * 8;
  size_t o = e >> 12;
  int nb = ((int)(e & 4095)) >> 5;
  float s = scales[o * NBLK_Q + nb];
  const int4* q = (const int4*)(qs + e);
  int4 q0 = q[0], q1 = q[1];
  u16x8 out;
  out[0] = f2bf(s * (float)q0.x);
  out[1] = f2bf(s * (float)q0.y);
  out[2] = f2bf(s * (float)q0.z);
  out[3] = f2bf(s * (float)q0.w);
  out[4] = f2bf(s * (float)q1.x);
  out[5] = f2bf(s * (float)q1.y);
  out[6] = f2bf(s * (float)q1.z);
  out[7] = f2bf(s * (float)q1.w);
  *(u16x8*)(W + e) = out;
}

// ---------------- main GEMM: C[M][N] = A[M][K] * Bt[N][K]^T + bias ----------------
// 256x256 tile, BK=64, 8 waves (2M x 4N), per-wave 128x64 output, 16x16x32 MFMA.
// 8-phase (4 phases/K-tile) schedule, T3+T4: per phase {stage 1 half-tile;
// [vmcnt(4) at p0]; barrier; ds_read subtile; setprio(1); 16 MFMA; setprio(0);
// barrier}. Counted vmcnt never 0 in the loop (up to 8 loads in flight).
// LDS: 2 buffers x 64KB, fragment-contiguous (1KB frags, 0 bank conflicts).
// Half-tile groups per K-tile: g0=A ks0, g1=A ks1, g2=B ks0, g3=B ks1 (16KB each).
// Stage schedule: kt phases stage q=4kt+5..4kt+8; q=4kt+8 writes current buffer's
// g0 at p3, safe because bar2_p2 follows all waves' last reads of that buffer.
// Tail: q clamped to 255 (duplicate stages write identical bytes -> benign).
__global__ __launch_bounds__(512, 2) void gemm_bt_bias(
    const unsigned short* __restrict__ A,   // [M][K] bf16
    const unsigned short* __restrict__ Bt,  // [N][K] bf16
    const float* __restrict__ bias,         // [N]
    float* __restrict__ C) {                // [M][N] fp32
  __shared__ char lds[131072];  // 2 x 64KB

  const int tid = threadIdx.x;
  const int w = tid >> 6;   // wave 0..7
  const int l = tid & 63;
  const int wm = w >> 2;    // M half
  const int wn = w & 3;     // N quarter
  const int sr = l & 15;
  const int sg = l >> 4;

  // XCD-chunked bijective grid mapping, mtile fastest (W-tiles L2-resident, A L3-resident)
  const int bid = blockIdx.x;
  const int wgid = (bid & 7) * 128 + (bid >> 3);
  const int mtile = wgid & 15;
  const int ntile = wgid >> 4;
  const int brow = mtile * BM;
  const int bcol = ntile * BN;

  // stage one 16KB half-tile group q (2 x global_load_lds per thread)
  auto stage = [&](int q) {
    q = (q > NGROUPS - 1) ? (NGROUPS - 1) : q;
    const int kt_s = q >> 2;
    const int g = q & 3;
    char* dst = lds + (kt_s & 1) * 65536 + g * 16384 + (w * 2) * 1024 + l * 16;
    const unsigned short* base = (g < 2) ? A : Bt;
    const int r0 = (g < 2) ? brow : bcol;
    const int kof = kt_s * BK + (g & 1) * 32 + sg * 8;
#pragma unroll
    for (int j = 0; j < 2; ++j)
      async_copy16(base + (size_t)(r0 + (w * 2 + j) * 16 + sr) * K_DIM + kof,
                   dst + j * 1024);
  };

  f32x4 acc[8][4] = {};
  bf16x8 pa[2][4];  // current A ih-half fragments (s, i) — reused ih0 -> ih1
  bf16x8 b[2][4];   // B fragments (s, j) for the whole K-tile

  // prologue: stage tile0 g0..g3 + tile1 g0
#pragma unroll
  for (int q = 0; q < 5; ++q) stage(q);

  for (int kt = 0; kt < KTILES; ++kt) {
    const char* bb = lds + (kt & 1) * 65536;

    // ---------------- phase 0: quadrant (ih0, jh0) ----------------
    stage(4 * kt + 5);
    asm volatile("s_waitcnt vmcnt(4)" ::: "memory");  // lands all of tile kt
    __builtin_amdgcn_s_barrier();
#pragma unroll
    for (int s = 0; s < 2; ++s) {
#pragma unroll
      for (int i = 0; i < 4; ++i)
        pa[s][i] = *(const bf16x8*)(bb + (s * 16 + wm * 8 + i) * 1024 + l * 16);
#pragma unroll
      for (int j = 0; j < 2; ++j)
        b[s][j] = *(const bf16x8*)(bb + 32768 + (s * 16 + wn * 4 + j) * 1024 + l * 16);
    }
    __builtin_amdgcn_s_setprio(1);
#pragma unroll
    for (int i = 0; i < 4; ++i)
#pragma unroll
      for (int j = 0; j < 2; ++j) {
        acc[i][j] = __builtin_amdgcn_mfma_f32_16x16x32_bf16(pa[0][i], b[0][j], acc[i][j], 0, 0, 0);
        acc[i][j] = __builtin_amdgcn_mfma_f32_16x16x32_bf16(pa[1][i], b[1][j], acc[i][j], 0, 0, 0);
      }
    __builtin_amdgcn_s_setprio(0);
    __builtin_amdgcn_s_barrier();

    // ---------------- phase 1: quadrant (ih0, jh1) ----------------
    stage(4 * kt + 6);
#pragma unroll
    for (int s = 0; s < 2; ++s)
#pragma unroll
      for (int j = 0; j < 2; ++j)
        b[s][2 + j] = *(const bf16x8*)(bb + 32768 + (s * 16 + wn * 4 + 2 + j) * 1024 + l * 16);
    __builtin_amdgcn_s_barrier();
    __builtin_amdgcn_s_setprio(1);
#pragma unroll
    for (int i = 0; i < 4; ++i)
#pragma unroll
      for (int j = 0; j < 2; ++j) {
        acc[i][2 + j] = __builtin_amdgcn_mfma_f32_16x16x32_bf16(pa[0][i], b[0][2 + j], acc[i][2 + j], 0, 0, 0);
        acc[i][2 + j] = __builtin_amdgcn_mfma_f32_16x16x32_bf16(pa[1][i], b[1][2 + j], acc[i][2 + j], 0, 0, 0);
      }
    __builtin_amdgcn_s_setprio(0);
    __builtin_amdgcn_s_barrier();

    // ---------------- phase 2: quadrant (ih1, jh0) ----------------
    stage(4 * kt + 7);
#pragma unroll
    for (int s = 0; s < 2; ++s)
#pragma unroll
      for (int i = 0; i < 4; ++i)
        pa[s][i] = *(const bf16x8*)(bb + (s * 16 + wm * 8 + 4 + i) * 1024 + l * 16);
    __builtin_amdgcn_s_barrier();
    __builtin_amdgcn_s_setprio(1);
#pragma unroll
    for (int i = 0; i < 4; ++i)
#pragma unroll
      for (int j = 0; j < 2; ++j) {
        acc[4 + i][j] = __builtin_amdgcn_mfma_f32_16x16x32_bf16(pa[0][i], b[0][j], acc[4 + i][j], 0, 0, 0);
        acc[4 + i][j] = __builtin_amdgcn_mfma_f32_16x16x32_bf16(pa[1][i], b[1][j], acc[4 + i][j], 0, 0, 0);
      }
    __builtin_amdgcn_s_setprio(0);
    __builtin_amdgcn_s_barrier();  // bar2_p2: all waves done reading this buffer

    // ---------------- phase 3: quadrant (ih1, jh1) ----------------
    stage(4 * kt + 8);  // writes current buffer g0 — safe post bar2_p2
    __builtin_amdgcn_s_barrier();
    __builtin_amdgcn_s_setprio(1);
#pragma unroll
    for (int i = 0; i < 4; ++i)
#pragma unroll
      for (int j = 0; j < 2; ++j) {
        acc[4 + i][2 + j] = __builtin_amdgcn_mfma_f32_16x16x32_bf16(pa[0][i], b[0][2 + j], acc[4 + i][2 + j], 0, 0, 0);
        acc[4 + i][2 + j] = __builtin_amdgcn_mfma_f32_16x16x32_bf16(pa[1][i], b[1][2 + j], acc[4 + i][2 + j], 0, 0, 0);
      }
    __builtin_amdgcn_s_setprio(0);
    __builtin_amdgcn_s_barrier();
  }

  asm volatile("s_waitcnt vmcnt(0)" ::: "memory");

  // epilogue: C/D layout col = lane&15, row = (lane>>4)*4 + t
#pragma unroll
  for (int j = 0; j < 4; ++j) {
    const int col = bcol + wn * 64 + j * 16 + sr;
    const float bv = bias[col];
#pragma unroll
    for (int i = 0; i < 8; ++i) {
      const int row = brow + wm * 128 + i * 16 + sg * 4;
#pragma unroll
      for (int t = 0; t < 4; ++t) {
        C[(size_t)(row + t) * N_DIM + col] = acc[i][j][t] + bv;
      }
    }
  }
}

// ---------------- fallback (ws too small): exact fp32, slow but correct ----------------
__global__ void naive_gemm(const float* __restrict__ x, const int* __restrict__ qs,
                           const float* __restrict__ scales, const float* __restrict__ bias,
                           float* __restrict__ y) {
  size_t idx = (size_t)blockIdx.x * 256 + threadIdx.x;
  if (idx >= (size_t)M_DIM * N_DIM) return;
  int o = (int)(idx % N_DIM);
  size_t m = idx / N_DIM;
  const float* xr = x + m * K_DIM;
  const int* q = qs + (size_t)o * K_DIM;
  const float* sc = scales + (size_t)o * NBLK_Q;
  float sum = 0.f;
  for (int nb = 0; nb < NBLK_Q; ++nb) {
    float s = sc[nb];
    float bs = 0.f;
#pragma unroll 8
    for (int b = 0; b < 32; ++b) bs += xr[nb * 32 + b] * (float)q[nb * 32 + b];
    sum += s * bs;
  }
  y[idx] = sum + bias[o];
}

extern "C" void kernel_launch(void* const* d_in, const int* in_sizes, int n_in,
                              void* d_out, int out_size, void* d_ws, size_t ws_size,
                              hipStream_t stream) {
  const float* x = (const float*)d_in[0];
  const int* qs = (const int*)d_in[1];
  const float* scales = (const float*)d_in[2];
  const float* bias = (const float*)d_in[3];
  float* y = (float*)d_out;

  const size_t A_bytes = (size_t)M_DIM * K_DIM * 2;  // 32 MB
  const size_t W_bytes = (size_t)N_DIM * K_DIM * 2;  // 128 MB

  if (ws_size < A_bytes + W_bytes) {
    size_t total = (size_t)M_DIM * N_DIM;
    naive_gemm<<<(unsigned)((total + 255) / 256), 256, 0, stream>>>(x, qs, scales, bias, y);
    return;
  }

  unsigned short* A = (unsigned short*)d_ws;
  unsigned short* W = (unsigned short*)((char*)d_ws + A_bytes);

  cvt_x_bf16<<<(M_DIM * K_DIM / 4) / 256, 256, 0, stream>>>((const float4*)x, (ushort4*)A);
  dequant_w<<<(int)(((size_t)N_DIM * K_DIM / 8) / 256), 256, 0, stream>>>(qs, scales, W);
  gemm_bt_bias<<<(M_DIM / BM) * (N_DIM / BN), 512, 0, stream>>>(A, W, bias, y);
}